// Round 4
// baseline (639.783 us; speedup 1.0000x reference)
//
#include <hip/hip_runtime.h>
#include <math.h>

#define NN 50000
#define EE 800000
#define INDIM 10
#define EMB 32
#define HID 128
#define NLAYERS 3
#define BN_EPS 1e-5f

#define SCAN_T 1024
#define PER_T ((NN + SCAN_T - 1) / SCAN_T)   // 49

__device__ __forceinline__ int clampN(int v) {
    return v < 0 ? 0 : (v >= NN ? NN - 1 : v);
}

// ---------------- setup kernels (graph structure, once per launch) ----------

__global__ void k_init(float* __restrict__ deg, int* __restrict__ cnt) {
    int i = blockIdx.x * blockDim.x + threadIdx.x;
    if (i < NN) { deg[i] = 1.0f; cnt[i] = 0; }   // self-loop weight 1.0
}

__global__ void k_edge_deg(const int* __restrict__ ei,
                           const float* __restrict__ ew,
                           float* __restrict__ deg, int* __restrict__ cnt) {
    int e = blockIdx.x * blockDim.x + threadIdx.x;
    if (e < EE) {
        int c = clampN(ei[EE + e]);               // target node
        atomicAdd(&deg[c], ew[e]);
        atomicAdd(&cnt[c], 1);
    }
}

__global__ void k_dinv(float* __restrict__ deg) {
    int i = blockIdx.x * blockDim.x + threadIdx.x;
    if (i < NN) {
        float d = deg[i];
        deg[i] = d > 0.f ? rsqrtf(d) : 0.f;       // in-place: deg -> dinv
    }
}

// thread-coarsened single-block exclusive scan: cnt -> offs; zeroes cursor
__global__ __launch_bounds__(1024) void k_scan(const int* __restrict__ cnt,
                                               int* __restrict__ offs,
                                               int* __restrict__ cursor) {
    __shared__ int sums[SCAN_T];
    int t = threadIdx.x;
    int base = t * PER_T;
    // pass 1: per-thread serial sum
    int s = 0;
    for (int i = 0; i < PER_T; ++i) {
        int idx = base + i;
        if (idx < NN) s += cnt[idx];
    }
    sums[t] = s;
    __syncthreads();
    // block scan (inclusive) over per-thread sums
    for (int o = 1; o < SCAN_T; o <<= 1) {
        int add = (t >= o) ? sums[t - o] : 0;
        __syncthreads();
        sums[t] += add;
        __syncthreads();
    }
    int run = (t == 0) ? 0 : sums[t - 1];         // exclusive carry
    // pass 2: write exclusive prefixes (cnt re-read is L2-hot)
    for (int i = 0; i < PER_T; ++i) {
        int idx = base + i;
        if (idx < NN) {
            offs[idx] = run;
            run += cnt[idx];
            cursor[idx] = 0;
        }
    }
    if (t == SCAN_T - 1) offs[NN] = sums[SCAN_T - 1];
}

__global__ void k_fill(const int* __restrict__ ei,
                       const float* __restrict__ ew,
                       const float* __restrict__ dinv,
                       const int* __restrict__ offs, int* __restrict__ cursor,
                       int* __restrict__ csr_src, float* __restrict__ csr_w) {
    int e = blockIdx.x * blockDim.x + threadIdx.x;
    if (e < EE) {
        int r = clampN(ei[e]);
        int c = clampN(ei[EE + e]);
        int pos = atomicAdd(&cursor[c], 1);
        int i = offs[c] + pos;
        i = i < 0 ? 0 : (i >= EE ? EE - 1 : i);   // defensive bound
        csr_src[i] = r;
        csr_w[i] = dinv[r] * ew[e] * dinv[c];
    }
}

// transpose conv_W[L][c][k] -> Wt[L][k][c]
__global__ void k_transpose(const float* __restrict__ W, float* __restrict__ Wt) {
    int idx = blockIdx.x * blockDim.x + threadIdx.x;
    if (idx < NLAYERS * HID * HID) {
        int L = idx >> 14;
        int rem = idx & 16383;
        int k = rem >> 7, c = rem & 127;
        Wt[idx] = W[L * 16384 + c * 128 + k];
    }
}

// ---------------- prologue: h = relu([emb, x@ftW.T+ftb] @ combW.T + combb) --

__global__ __launch_bounds__(256) void k_init_h(
        const float* __restrict__ x, const float* __restrict__ emb,
        const float* __restrict__ ftW, const float* __restrict__ ftb,
        const float* __restrict__ combW, const float* __restrict__ combb,
        float* __restrict__ h) {
    __shared__ float Wsh[HID * 65];               // stride 65: conflict-free
    __shared__ float csh[4][64];
    int t = threadIdx.x;
    #pragma unroll
    for (int i = 0; i < 32; ++i) {
        int s = i * 256 + t;                      // 0..8191
        Wsh[(s >> 6) * 65 + (s & 63)] = combW[s];
    }
    int w = t >> 6, l = t & 63;
    int n = blockIdx.x * 4 + w;
    bool valid = n < NN;
    if (valid) {
        if (l < 32) {
            csh[w][l] = emb[n * EMB + l];
        } else {
            int j = l - 32;
            float acc = ftb[j];
            #pragma unroll
            for (int k = 0; k < INDIM; ++k) {
                float xv = x[n * INDIM + k];
                // robust nan_to_num (survives fast-math)
                unsigned bits = __float_as_uint(xv) & 0x7fffffffu;
                if (bits > 0x7f800000u) xv = 0.f;
                acc = fmaf(ftW[j * INDIM + k], xv, acc);
            }
            csh[w][l] = acc;
        }
    }
    __syncthreads();
    if (valid) {
        #pragma unroll
        for (int half = 0; half < 2; ++half) {
            int c = l + half * 64;
            float acc = combb[c];
            const float* wr = &Wsh[c * 65];
            #pragma unroll
            for (int k = 0; k < 64; ++k) acc = fmaf(wr[k], csh[w][k], acc);
            h[n * HID + c] = fmaxf(acc, 0.f);
        }
    }
}

// ---------------- per-layer GEMM: xt = h @ W.T  (via Wt[k][c]) --------------

#define BM 64
__global__ __launch_bounds__(256) void k_gemm(const float* __restrict__ h,
                                              const float* __restrict__ Wt,
                                              float* __restrict__ xt) {
    __shared__ float hsh[BM * 132];               // stride 132: 2-way (free)
    int t = threadIdx.x;
    int row0 = blockIdx.x * BM;
    #pragma unroll
    for (int i = 0; i < 8; ++i) {
        int s = i * 256 + t;                      // float4 index 0..2047
        int r = s >> 5;                           // 32 float4 per row
        int cc = s & 31;
        float4 v = make_float4(0.f, 0.f, 0.f, 0.f);
        int row = row0 + r;
        if (row < NN) v = *(const float4*)&h[row * HID + cc * 4];
        *(float4*)&hsh[r * 132 + cc * 4] = v;
    }
    __syncthreads();
    int ty = t >> 4, tx = t & 15;
    float acc[4][8];
    #pragma unroll
    for (int i = 0; i < 4; ++i)
        #pragma unroll
        for (int j = 0; j < 8; ++j) acc[i][j] = 0.f;

    for (int k0 = 0; k0 < HID; k0 += 4) {
        float wf[4][8];
        #pragma unroll
        for (int kk = 0; kk < 4; ++kk) {
            float4 a = *(const float4*)&Wt[(k0 + kk) * HID + tx * 8];
            float4 b = *(const float4*)&Wt[(k0 + kk) * HID + tx * 8 + 4];
            wf[kk][0] = a.x; wf[kk][1] = a.y; wf[kk][2] = a.z; wf[kk][3] = a.w;
            wf[kk][4] = b.x; wf[kk][5] = b.y; wf[kk][6] = b.z; wf[kk][7] = b.w;
        }
        float hf[4][4];
        #pragma unroll
        for (int i = 0; i < 4; ++i) {
            float4 hv = *(const float4*)&hsh[(ty * 4 + i) * 132 + k0];
            hf[i][0] = hv.x; hf[i][1] = hv.y; hf[i][2] = hv.z; hf[i][3] = hv.w;
        }
        #pragma unroll
        for (int i = 0; i < 4; ++i)
            #pragma unroll
            for (int kk = 0; kk < 4; ++kk)
                #pragma unroll
                for (int j = 0; j < 8; ++j)
                    acc[i][j] = fmaf(hf[i][kk], wf[kk][j], acc[i][j]);
    }
    #pragma unroll
    for (int i = 0; i < 4; ++i) {
        int row = row0 + ty * 4 + i;
        if (row < NN) {
            *(float4*)&xt[row * HID + tx * 8] =
                make_float4(acc[i][0], acc[i][1], acc[i][2], acc[i][3]);
            *(float4*)&xt[row * HID + tx * 8 + 4] =
                make_float4(acc[i][4], acc[i][5], acc[i][6], acc[i][7]);
        }
    }
}

// ------- aggregation + self-loop + bias + relu + BN + residual (in-place h) -

__global__ __launch_bounds__(256) void k_aggregate(
        const float* __restrict__ xt, float* __restrict__ h,
        const int* __restrict__ offs, const int* __restrict__ csr_src,
        const float* __restrict__ csr_w, const float* __restrict__ dinv,
        const float* __restrict__ bias, const float* __restrict__ gamma,
        const float* __restrict__ beta, const float* __restrict__ mean,
        const float* __restrict__ var) {
    int n = blockIdx.x * 4 + (threadIdx.x >> 6);
    int l = threadIdx.x & 63;
    if (n >= NN) return;
    const float2* xt2 = (const float2*)xt;
    float2 accA = make_float2(0.f, 0.f);
    float2 accB = make_float2(0.f, 0.f);
    int s0 = offs[n], s1 = offs[n + 1];
    int i = s0;
    for (; i + 3 < s1; i += 4) {                 // 4 gathers in flight
        int sa = csr_src[i],     sb = csr_src[i + 1];
        int sc = csr_src[i + 2], sd = csr_src[i + 3];
        float wa = csr_w[i],     wb = csr_w[i + 1];
        float wc = csr_w[i + 2], wd = csr_w[i + 3];
        float2 va = xt2[(size_t)sa * 64 + l];
        float2 vb = xt2[(size_t)sb * 64 + l];
        float2 vc = xt2[(size_t)sc * 64 + l];
        float2 vd = xt2[(size_t)sd * 64 + l];
        accA.x = fmaf(va.x, wa, accA.x); accA.y = fmaf(va.y, wa, accA.y);
        accB.x = fmaf(vb.x, wb, accB.x); accB.y = fmaf(vb.y, wb, accB.y);
        accA.x = fmaf(vc.x, wc, accA.x); accA.y = fmaf(vc.y, wc, accA.y);
        accB.x = fmaf(vd.x, wd, accB.x); accB.y = fmaf(vd.y, wd, accB.y);
    }
    for (; i < s1; ++i) {
        int src = csr_src[i];
        float wgt = csr_w[i];
        float2 v = xt2[(size_t)src * 64 + l];
        accA.x = fmaf(v.x, wgt, accA.x); accA.y = fmaf(v.y, wgt, accA.y);
    }
    float di = dinv[n];
    float sw = di * di;                            // self-loop norm
    float2 vs = xt2[(size_t)n * 64 + l];
    accA.x = fmaf(vs.x, sw, accA.x); accA.y = fmaf(vs.y, sw, accA.y);
    float ax = accA.x + accB.x, ay = accA.y + accB.y;

    int c0 = 2 * l, c1 = c0 + 1;
    float v0 = fmaxf(ax + bias[c0], 0.f);
    float v1 = fmaxf(ay + bias[c1], 0.f);
    v0 = (v0 - mean[c0]) * rsqrtf(var[c0] + BN_EPS) * gamma[c0] + beta[c0];
    v1 = (v1 - mean[c1]) * rsqrtf(var[c1] + BN_EPS) * gamma[c1] + beta[c1];
    float2 hv = *(const float2*)&h[n * HID + c0];
    float2 outv = make_float2(v0 + hv.x, v1 + hv.y);
    *(float2*)&h[n * HID + c0] = outv;
}

// ---------------- final: out = clip(h @ linW.T + linb) ----------------------

__global__ __launch_bounds__(256) void k_final(const float* __restrict__ h,
                                               const float* __restrict__ linW,
                                               const float* __restrict__ linb,
                                               float* __restrict__ out) {
    int n = blockIdx.x * 4 + (threadIdx.x >> 6);
    int l = threadIdx.x & 63;
    if (n >= NN) return;
    const float2* h2 = (const float2*)h;
    const float2* w2 = (const float2*)linW;
    float2 hv = h2[(size_t)n * 64 + l];
    float2 wv = w2[l];
    float s = hv.x * wv.x + hv.y * wv.y;
    #pragma unroll
    for (int off = 32; off; off >>= 1) s += __shfl_xor(s, off, 64);
    if (l == 0) {
        float o = s + linb[0];
        o = fminf(fmaxf(o, -10.f), 10.f);
        out[n] = o;
    }
}

// ---------------- launch ----------------------------------------------------

extern "C" void kernel_launch(void* const* d_in, const int* in_sizes, int n_in,
                              void* d_out, int out_size, void* d_ws, size_t ws_size,
                              hipStream_t stream) {
    const float* x     = (const float*)d_in[0];
    const int*   ei    = (const int*)d_in[1];     // int32: harness narrows int64
    const float* ew    = (const float*)d_in[2];
    const float* emb   = (const float*)d_in[3];
    const float* ftW   = (const float*)d_in[4];
    const float* ftb   = (const float*)d_in[5];
    const float* combW = (const float*)d_in[6];
    const float* combb = (const float*)d_in[7];
    const float* convW = (const float*)d_in[8];
    const float* convb = (const float*)d_in[9];
    const float* gamma = (const float*)d_in[10];
    const float* beta  = (const float*)d_in[11];
    const float* mean  = (const float*)d_in[12];
    const float* var   = (const float*)d_in[13];
    const float* linW  = (const float*)d_in[14];
    const float* linb  = (const float*)d_in[15];
    float* out = (float*)d_out;

    char* ws = (char*)d_ws;
    size_t off = 0;
    auto alloc = [&](size_t bytes) {
        void* p = ws + off;
        off = (off + bytes + 255) & ~(size_t)255;
        return p;
    };
    float* h       = (float*)alloc((size_t)NN * HID * 4);
    float* xt      = (float*)alloc((size_t)NN * HID * 4);
    float* dinv    = (float*)alloc((size_t)NN * 4);      // deg, then rsqrt in-place
    int*   offs    = (int*)alloc((size_t)(NN + 1) * 4);
    int*   cnt     = (int*)alloc((size_t)NN * 4);        // counts, then cursor
    int*   csr_src = (int*)alloc((size_t)EE * 4);
    float* csr_w   = (float*)alloc((size_t)EE * 4);
    float* Wt      = (float*)alloc((size_t)NLAYERS * HID * HID * 4);

    const int NB = (NN + 255) / 256;         // 196
    const int EB = (EE + 255) / 256;         // 3125
    const int NODE4 = (NN + 3) / 4;          // 12500

    k_init<<<NB, 256, 0, stream>>>(dinv, cnt);
    k_edge_deg<<<EB, 256, 0, stream>>>(ei, ew, dinv, cnt);
    k_dinv<<<NB, 256, 0, stream>>>(dinv);
    k_scan<<<1, SCAN_T, 0, stream>>>(cnt, offs, cnt);
    k_fill<<<EB, 256, 0, stream>>>(ei, ew, dinv, offs, cnt, csr_src, csr_w);
    k_init_h<<<NODE4, 256, 0, stream>>>(x, emb, ftW, ftb, combW, combb, h);
    k_transpose<<<(NLAYERS * HID * HID + 255) / 256, 256, 0, stream>>>(convW, Wt);
    for (int L = 0; L < NLAYERS; ++L) {
        k_gemm<<<(NN + BM - 1) / BM, 256, 0, stream>>>(h, Wt + L * HID * HID, xt);
        k_aggregate<<<NODE4, 256, 0, stream>>>(xt, h, offs, csr_src, csr_w, dinv,
                                               convb + L * HID, gamma, beta, mean, var);
    }
    k_final<<<NODE4, 256, 0, stream>>>(h, linW, linb, out);
}

// Round 7
// 524.329 us; speedup vs baseline: 1.2202x; 1.2202x over previous
//
#include <hip/hip_runtime.h>
#include <math.h>

#define NN 50000
#define EE 800000
#define INDIM 10
#define EMB 32
#define HID 128
#define NLAYERS 3
#define BN_EPS 1e-5f

#define SB 256
#define NB ((NN + SB - 1) / SB)              // 196 scan blocks

__device__ __forceinline__ int clampN(int v) {
    return v < 0 ? 0 : (v >= NN ? NN - 1 : v);
}

// ---------------- setup kernels (graph structure, once per launch) ----------

__global__ void k_init(float* __restrict__ deg, int* __restrict__ cnt) {
    int i = blockIdx.x * blockDim.x + threadIdx.x;
    if (i < NN) { deg[i] = 1.0f; cnt[i] = 0; }   // self-loop weight 1.0
}

__global__ void k_edge_deg(const int* __restrict__ ei,
                           const float* __restrict__ ew,
                           float* __restrict__ deg, int* __restrict__ cnt) {
    int e = blockIdx.x * blockDim.x + threadIdx.x;
    if (e < EE) {
        int c = clampN(ei[EE + e]);               // target node
        atomicAdd(&deg[c], ew[e]);
        atomicAdd(&cnt[c], 1);
    }
}

__global__ void k_dinv(float* __restrict__ deg) {
    int i = blockIdx.x * blockDim.x + threadIdx.x;
    if (i < NN) {
        float d = deg[i];
        deg[i] = d > 0.f ? rsqrtf(d) : 0.f;       // in-place: deg -> dinv
    }
}

// ---- device-wide scan, 3 stages, all coalesced ----

__global__ __launch_bounds__(SB) void k_bsum(const int* __restrict__ cnt,
                                             int* __restrict__ bsum) {
    int i = blockIdx.x * SB + threadIdx.x;
    int v = (i < NN) ? cnt[i] : 0;
    #pragma unroll
    for (int o = 32; o; o >>= 1) v += __shfl_down(v, o, 64);
    __shared__ int wsum[4];
    int w = threadIdx.x >> 6, l = threadIdx.x & 63;
    if (l == 0) wsum[w] = v;
    __syncthreads();
    if (threadIdx.x == 0)
        bsum[blockIdx.x] = wsum[0] + wsum[1] + wsum[2] + wsum[3];
}

__global__ __launch_bounds__(SB) void k_bscan(const int* __restrict__ bsum,
                                              int* __restrict__ boffs) {
    __shared__ int sh[SB];
    int t = threadIdx.x;
    int v = (t < NB) ? bsum[t] : 0;
    sh[t] = v;
    __syncthreads();
    for (int o = 1; o < SB; o <<= 1) {
        int a = (t >= o) ? sh[t - o] : 0;
        __syncthreads();
        sh[t] += a;
        __syncthreads();
    }
    if (t < NB) boffs[t] = sh[t] - v;             // exclusive
}

__global__ __launch_bounds__(SB) void k_scan2(const int* __restrict__ cnt,
                                              const int* __restrict__ boffs,
                                              int* __restrict__ offs,
                                              int* __restrict__ cursor) {
    __shared__ int sh[SB];
    int t = threadIdx.x;
    int i = blockIdx.x * SB + t;
    int v = (i < NN) ? cnt[i] : 0;
    sh[t] = v;
    __syncthreads();
    for (int o = 1; o < SB; o <<= 1) {
        int a = (t >= o) ? sh[t - o] : 0;
        __syncthreads();
        sh[t] += a;
        __syncthreads();
    }
    if (i < NN) {
        offs[i] = boffs[blockIdx.x] + sh[t] - v;  // exclusive prefix
        cursor[i] = 0;
    }
    if (i == 0) offs[NN] = EE;                    // total is exact by construction
}

__global__ void k_fill(const int* __restrict__ ei,
                       const float* __restrict__ ew,
                       const float* __restrict__ dinv,
                       const int* __restrict__ offs, int* __restrict__ cursor,
                       int* __restrict__ csr_src, float* __restrict__ csr_w) {
    int e = blockIdx.x * blockDim.x + threadIdx.x;
    if (e < EE) {
        int r = clampN(ei[e]);
        int c = clampN(ei[EE + e]);
        int pos = atomicAdd(&cursor[c], 1);
        int i = offs[c] + pos;
        i = i < 0 ? 0 : (i >= EE ? EE - 1 : i);   // defensive bound
        csr_src[i] = r;
        csr_w[i] = dinv[r] * ew[e] * dinv[c];
    }
}

// transpose conv_W[L][c][k] -> Wt[L][k][c]
__global__ void k_transpose(const float* __restrict__ W, float* __restrict__ Wt) {
    int idx = blockIdx.x * blockDim.x + threadIdx.x;
    if (idx < NLAYERS * HID * HID) {
        int L = idx >> 14;
        int rem = idx & 16383;
        int k = rem >> 7, c = rem & 127;
        Wt[idx] = W[L * 16384 + c * 128 + k];
    }
}

// ---------------- prologue: h = relu([emb, x@ftW.T+ftb] @ combW.T + combb) --

__global__ __launch_bounds__(256) void k_init_h(
        const float* __restrict__ x, const float* __restrict__ emb,
        const float* __restrict__ ftW, const float* __restrict__ ftb,
        const float* __restrict__ combW, const float* __restrict__ combb,
        float* __restrict__ h) {
    __shared__ float Wsh[HID * 65];               // stride 65: conflict-free
    __shared__ float csh[4][64];
    int t = threadIdx.x;
    #pragma unroll
    for (int i = 0; i < 32; ++i) {
        int s = i * 256 + t;                      // 0..8191
        Wsh[(s >> 6) * 65 + (s & 63)] = combW[s];
    }
    int w = t >> 6, l = t & 63;
    int n = blockIdx.x * 4 + w;
    bool valid = n < NN;
    if (valid) {
        if (l < 32) {
            csh[w][l] = emb[n * EMB + l];
        } else {
            int j = l - 32;
            float acc = ftb[j];
            #pragma unroll
            for (int k = 0; k < INDIM; ++k) {
                float xv = x[n * INDIM + k];
                // robust nan_to_num (survives fast-math)
                unsigned bits = __float_as_uint(xv) & 0x7fffffffu;
                if (bits > 0x7f800000u) xv = 0.f;
                acc = fmaf(ftW[j * INDIM + k], xv, acc);
            }
            csh[w][l] = acc;
        }
    }
    __syncthreads();
    if (valid) {
        #pragma unroll
        for (int half = 0; half < 2; ++half) {
            int c = l + half * 64;
            float acc = combb[c];
            const float* wr = &Wsh[c * 65];
            #pragma unroll
            for (int k = 0; k < 64; ++k) acc = fmaf(wr[k], csh[w][k], acc);
            h[n * HID + c] = fmaxf(acc, 0.f);
        }
    }
}

// ---------------- per-layer GEMM: xt = h @ W.T  (via Wt[k][c]) --------------

#define BM 64
__global__ __launch_bounds__(256) void k_gemm(const float* __restrict__ h,
                                              const float* __restrict__ Wt,
                                              float* __restrict__ xt) {
    __shared__ float hsh[BM * 132];               // stride 132: 2-way (free)
    int t = threadIdx.x;
    int row0 = blockIdx.x * BM;
    #pragma unroll
    for (int i = 0; i < 8; ++i) {
        int s = i * 256 + t;                      // float4 index 0..2047
        int r = s >> 5;                           // 32 float4 per row
        int cc = s & 31;
        float4 v = make_float4(0.f, 0.f, 0.f, 0.f);
        int row = row0 + r;
        if (row < NN) v = *(const float4*)&h[row * HID + cc * 4];
        *(float4*)&hsh[r * 132 + cc * 4] = v;
    }
    __syncthreads();
    int ty = t >> 4, tx = t & 15;
    float acc[4][8];
    #pragma unroll
    for (int i = 0; i < 4; ++i)
        #pragma unroll
        for (int j = 0; j < 8; ++j) acc[i][j] = 0.f;

    for (int k0 = 0; k0 < HID; k0 += 4) {
        float wf[4][8];
        #pragma unroll
        for (int kk = 0; kk < 4; ++kk) {
            float4 a = *(const float4*)&Wt[(k0 + kk) * HID + tx * 8];
            float4 b = *(const float4*)&Wt[(k0 + kk) * HID + tx * 8 + 4];
            wf[kk][0] = a.x; wf[kk][1] = a.y; wf[kk][2] = a.z; wf[kk][3] = a.w;
            wf[kk][4] = b.x; wf[kk][5] = b.y; wf[kk][6] = b.z; wf[kk][7] = b.w;
        }
        float hf[4][4];
        #pragma unroll
        for (int i = 0; i < 4; ++i) {
            float4 hv = *(const float4*)&hsh[(ty * 4 + i) * 132 + k0];
            hf[i][0] = hv.x; hf[i][1] = hv.y; hf[i][2] = hv.z; hf[i][3] = hv.w;
        }
        #pragma unroll
        for (int i = 0; i < 4; ++i)
            #pragma unroll
            for (int kk = 0; kk < 4; ++kk)
                #pragma unroll
                for (int j = 0; j < 8; ++j)
                    acc[i][j] = fmaf(hf[i][kk], wf[kk][j], acc[i][j]);
    }
    #pragma unroll
    for (int i = 0; i < 4; ++i) {
        int row = row0 + ty * 4 + i;
        if (row < NN) {
            *(float4*)&xt[row * HID + tx * 8] =
                make_float4(acc[i][0], acc[i][1], acc[i][2], acc[i][3]);
            *(float4*)&xt[row * HID + tx * 8 + 4] =
                make_float4(acc[i][4], acc[i][5], acc[i][6], acc[i][7]);
        }
    }
}

// ------- aggregation + self-loop + bias + relu + BN + residual (in-place h) -

__global__ __launch_bounds__(256) void k_aggregate(
        const float* __restrict__ xt, float* __restrict__ h,
        const int* __restrict__ offs, const int* __restrict__ csr_src,
        const float* __restrict__ csr_w, const float* __restrict__ dinv,
        const float* __restrict__ bias, const float* __restrict__ gamma,
        const float* __restrict__ beta, const float* __restrict__ mean,
        const float* __restrict__ var) {
    int n = blockIdx.x * 4 + (threadIdx.x >> 6);
    int l = threadIdx.x & 63;
    if (n >= NN) return;
    const float2* xt2 = (const float2*)xt;
    float2 accA = make_float2(0.f, 0.f);
    float2 accB = make_float2(0.f, 0.f);
    int s0 = offs[n], s1 = offs[n + 1];
    int i = s0;
    for (; i + 3 < s1; i += 4) {                 // 4 gathers in flight
        int sa = csr_src[i],     sb = csr_src[i + 1];
        int sc = csr_src[i + 2], sd = csr_src[i + 3];
        float wa = csr_w[i],     wb = csr_w[i + 1];
        float wc = csr_w[i + 2], wd = csr_w[i + 3];
        float2 va = xt2[(size_t)sa * 64 + l];
        float2 vb = xt2[(size_t)sb * 64 + l];
        float2 vc = xt2[(size_t)sc * 64 + l];
        float2 vd = xt2[(size_t)sd * 64 + l];
        accA.x = fmaf(va.x, wa, accA.x); accA.y = fmaf(va.y, wa, accA.y);
        accB.x = fmaf(vb.x, wb, accB.x); accB.y = fmaf(vb.y, wb, accB.y);
        accA.x = fmaf(vc.x, wc, accA.x); accA.y = fmaf(vc.y, wc, accA.y);
        accB.x = fmaf(vd.x, wd, accB.x); accB.y = fmaf(vd.y, wd, accB.y);
    }
    for (; i < s1; ++i) {
        int src = csr_src[i];
        float wgt = csr_w[i];
        float2 v = xt2[(size_t)src * 64 + l];
        accA.x = fmaf(v.x, wgt, accA.x); accA.y = fmaf(v.y, wgt, accA.y);
    }
    float di = dinv[n];
    float sw = di * di;                            // self-loop norm
    float2 vs = xt2[(size_t)n * 64 + l];
    accA.x = fmaf(vs.x, sw, accA.x); accA.y = fmaf(vs.y, sw, accA.y);
    float ax = accA.x + accB.x, ay = accA.y + accB.y;

    int c0 = 2 * l, c1 = c0 + 1;
    float v0 = fmaxf(ax + bias[c0], 0.f);
    float v1 = fmaxf(ay + bias[c1], 0.f);
    v0 = (v0 - mean[c0]) * rsqrtf(var[c0] + BN_EPS) * gamma[c0] + beta[c0];
    v1 = (v1 - mean[c1]) * rsqrtf(var[c1] + BN_EPS) * gamma[c1] + beta[c1];
    float2 hv = *(const float2*)&h[n * HID + c0];
    float2 outv = make_float2(v0 + hv.x, v1 + hv.y);
    *(float2*)&h[n * HID + c0] = outv;
}

// ---------------- final: out = clip(h @ linW.T + linb) ----------------------

__global__ __launch_bounds__(256) void k_final(const float* __restrict__ h,
                                               const float* __restrict__ linW,
                                               const float* __restrict__ linb,
                                               float* __restrict__ out) {
    int n = blockIdx.x * 4 + (threadIdx.x >> 6);
    int l = threadIdx.x & 63;
    if (n >= NN) return;
    const float2* h2 = (const float2*)h;
    const float2* w2 = (const float2*)linW;
    float2 hv = h2[(size_t)n * 64 + l];
    float2 wv = w2[l];
    float s = hv.x * wv.x + hv.y * wv.y;
    #pragma unroll
    for (int off = 32; off; off >>= 1) s += __shfl_xor(s, off, 64);
    if (l == 0) {
        float o = s + linb[0];
        o = fminf(fmaxf(o, -10.f), 10.f);
        out[n] = o;
    }
}

// ---------------- launch ----------------------------------------------------

extern "C" void kernel_launch(void* const* d_in, const int* in_sizes, int n_in,
                              void* d_out, int out_size, void* d_ws, size_t ws_size,
                              hipStream_t stream) {
    const float* x     = (const float*)d_in[0];
    const int*   ei    = (const int*)d_in[1];     // int32: harness narrows int64
    const float* ew    = (const float*)d_in[2];
    const float* emb   = (const float*)d_in[3];
    const float* ftW   = (const float*)d_in[4];
    const float* ftb   = (const float*)d_in[5];
    const float* combW = (const float*)d_in[6];
    const float* combb = (const float*)d_in[7];
    const float* convW = (const float*)d_in[8];
    const float* convb = (const float*)d_in[9];
    const float* gamma = (const float*)d_in[10];
    const float* beta  = (const float*)d_in[11];
    const float* mean  = (const float*)d_in[12];
    const float* var   = (const float*)d_in[13];
    const float* linW  = (const float*)d_in[14];
    const float* linb  = (const float*)d_in[15];
    float* out = (float*)d_out;

    char* ws = (char*)d_ws;
    size_t off = 0;
    auto alloc = [&](size_t bytes) {
        void* p = ws + off;
        off = (off + bytes + 255) & ~(size_t)255;
        return p;
    };
    float* h       = (float*)alloc((size_t)NN * HID * 4);
    float* xt      = (float*)alloc((size_t)NN * HID * 4);
    float* dinv    = (float*)alloc((size_t)NN * 4);      // deg, then rsqrt in-place
    int*   offs    = (int*)alloc((size_t)(NN + 1) * 4);
    int*   cnt     = (int*)alloc((size_t)NN * 4);        // counts, then cursor
    int*   csr_src = (int*)alloc((size_t)EE * 4);
    float* csr_w   = (float*)alloc((size_t)EE * 4);
    float* Wt      = (float*)alloc((size_t)NLAYERS * HID * HID * 4);
    int*   bsum    = (int*)alloc((size_t)(NB + 1) * 4);
    int*   boffs   = (int*)alloc((size_t)(NB + 1) * 4);

    const int NBK = (NN + 255) / 256;        // 196
    const int EB = (EE + 255) / 256;         // 3125
    const int NODE4 = (NN + 3) / 4;          // 12500

    k_init<<<NBK, 256, 0, stream>>>(dinv, cnt);
    k_edge_deg<<<EB, 256, 0, stream>>>(ei, ew, dinv, cnt);
    k_dinv<<<NBK, 256, 0, stream>>>(dinv);
    k_bsum<<<NB, SB, 0, stream>>>(cnt, bsum);
    k_bscan<<<1, SB, 0, stream>>>(bsum, boffs);
    k_scan2<<<NB, SB, 0, stream>>>(cnt, boffs, offs, cnt);
    k_fill<<<EB, 256, 0, stream>>>(ei, ew, dinv, offs, cnt, csr_src, csr_w);
    k_init_h<<<NODE4, 256, 0, stream>>>(x, emb, ftW, ftb, combW, combb, h);
    k_transpose<<<(NLAYERS * HID * HID + 255) / 256, 256, 0, stream>>>(convW, Wt);
    for (int L = 0; L < NLAYERS; ++L) {
        k_gemm<<<(NN + BM - 1) / BM, 256, 0, stream>>>(h, Wt + L * HID * HID, xt);
        k_aggregate<<<NODE4, 256, 0, stream>>>(xt, h, offs, csr_src, csr_w, dinv,
                                               convb + L * HID, gamma, beta, mean, var);
    }
    k_final<<<NODE4, 256, 0, stream>>>(h, linW, linb, out);
}